// Round 5
// baseline (2451.935 us; speedup 1.0000x reference)
//
#include <hip/hip_runtime.h>
#include <stdint.h>

#define Tn 100
#define Dn 51
#define Hn 128
#define G4 512     // 4*H
#define BR 8       // batch rows per workgroup
#define NWG 256    // workgroups (2048 / 8)
#define NTH 512    // 8 waves: wave w owns N-tiles {w,w+8,w+16,w+24} = gates i,f,g,o of cols [16w,16w+16)
#define RP 264     // xhA row stride in bf16 elems (16B-aligned rows)
#define SLOT 16384 // ring slot: one K-slice (32 tiles x 1KB) in u16 elems

typedef unsigned int uint32;
typedef unsigned short u16;
typedef short s16x8 __attribute__((ext_vector_type(8)));   // 8 bf16 = 4 VGPRs
typedef float f32x4v __attribute__((ext_vector_type(4)));

__device__ __forceinline__ float rcp_(float x){ return __builtin_amdgcn_rcpf(x); }
__device__ __forceinline__ float sigm(float x){ return rcp_(1.f + __expf(-x)); }
__device__ __forceinline__ float tanh_(float x){ return 1.f - 2.f*rcp_(1.f + __expf(2.f*x)); }

// fp32 -> bf16 round-to-nearest-even
__device__ __forceinline__ u16 f2bf(float f){
  uint32 u = __float_as_uint(f);
  return (u16)((u + 0x7fffu + ((u >> 16) & 1u)) >> 16);
}
__device__ __forceinline__ float bf2f(u16 u){ return __uint_as_float(((uint32)u)<<16); }

// A-fragment trick: row r (0..7) = bf16-hi of xh row r; row r+8 = bf16-lo.
// One MFMA computes both pumps; epilogue sums D[r] + D[r+8] via shfl.
__device__ __forceinline__ void wr_xh(u16* __restrict__ xhA, int r, int k, float v){
  u16 h = f2bf(v);
  xhA[r*RP + k]     = h;
  xhA[(r+8)*RP + k] = f2bf(v - bf2f(h));
}

struct WP {
  const float* W[6];   // [4H, din]  enc0..2, dec0..2 (fp32)
  const float* U[6];   // [4H, H]
  const float* Bb[6];  // [4H]
  const float* fW;     // [D, H]
  const float* fb;     // [D]
};

// ws: wsw = MFMA-B-fragment-swizzled bf16 weights.
// Layout per layer (uniform 131072 u16): block (n,s) at ((n*8+s)*64+lane)*8+j,
// holding Wc[k = s*32+(lane>>4)*8+j][c = n*16+(lane&15)], Wc = [Wih | Whh] along k,
// zero-padded (k>=K or s>=S). Chunk (n,s) is a contiguous 1KB = one wave's
// global_load_lds batch (64 lanes x 16B).
// fwtT: fW padded to [64][132] f32 (row d = output col; pad k 128..131 and
// d>=51 zero) -- proj reads row d per lane, b128.
#define FWTE (64*132)
#define PREP_TOTAL (6*131072 + 6*512 + FWTE + 64)
__global__ void prep_kernel(WP p, u16* __restrict__ wsw, float* __restrict__ bias,
                            float* __restrict__ fwt, float* __restrict__ fbw)
{
  int gid = blockIdx.x*256 + threadIdx.x;
  if (gid >= PREP_TOTAL) return;
  if (gid < 6*131072){
    int l = gid >> 17;
    int e = gid & 131071;
    int n    = e >> 12;
    int s    = (e >> 9) & 7;
    int lane = (e >> 3) & 63;
    int j    = e & 7;
    int k = s*32 + (lane >> 4)*8 + j;
    int c = n*16 + (lane & 15);
    int din = (l % 3 == 0) ? Dn : Hn;
    int K = din + Hn;
    u16 v = 0;
    if (k < K){
      float f = (k < din) ? p.W[l][(size_t)c*din + k] : p.U[l][(size_t)c*Hn + (k - din)];
      v = f2bf(f);
    }
    wsw[gid] = v;
  } else if (gid < 6*131072 + 6*512){
    int i = gid - 6*131072;
    bias[i] = p.Bb[i>>9][i & 511];
  } else if (gid < 6*131072 + 6*512 + FWTE){
    int i = gid - (6*131072 + 6*512);
    int d = i / 132, k = i % 132;
    fwt[i] = (k < Hn && d < Dn) ? p.fW[(size_t)d*Hn + k] : 0.f;
  } else {
    int d = gid - (6*131072 + 6*512 + FWTE);
    fbw[d] = (d < Dn) ? p.fb[d] : 0.f;
  }
}

// One 16B-per-lane async global->LDS batch = one (tile n, slice ts) 1KB chunk.
// LDS dest is wave-uniform base + lane*16 (m104); source is per-lane.
__device__ __forceinline__ void dma_tile(const u16* __restrict__ ws, u16* __restrict__ dslot,
                                         int n, int ts, int lane){
  const u16* g = ws + (((size_t)(n*8 + ts)) << 9) + (lane << 3);
  u16* l = dslot + (n << 9);
  __builtin_amdgcn_global_load_lds((const __attribute__((address_space(1))) uint32*)g,
                                   (__attribute__((address_space(3))) uint32*)l, 16, 0, 0);
}

// LDS-only barrier: NEVER drains vmcnt -> weight DMAs stay in flight across it.
__device__ __forceinline__ void bar_lds(){
  asm volatile("s_waitcnt lgkmcnt(0)" ::: "memory");
  __builtin_amdgcn_s_barrier();
}

// One fused layer-step: gemm (S-slice pipeline vs the LDS weight ring) +
// in-register activation + h distribution. Ring protocol (per-wave private —
// wave w only ever DMAs/reads tiles {w,w+8,w+16,w+24}, so NO barriers between
// sub-phases, only per-wave counted vmcnt):
//   sub-phase: vmcnt(8)  [drains the slice due in slot `slot`: 12 outstanding -> 8]
//              ds_read A-frag + 4 B-frags from slot `slot`
//              lgkmcnt(0)            [reads returned before overwrite]
//              DMA slice k+3 into slot `slot` (the just-freed slot: by cyclic
//              advance it is exactly the slot read 3 sub-phases from now)
//              4 MFMAs (i,f,g,o accumulate); slot = (slot+1)%3
// R4 BUG FIX: `slot` is a RUNNING counter threaded across ALL layer_steps.
// The old per-layer k%3 restart shifted the phase by S%3 per layer (S=8 -> 2),
// so later layers consumed rotated K-slices -> absmax 2e-2. With a persistent
// counter the "DMA into just-read slot" invariant is ring-correct for any S.
// Slices in flight stay pending across the epilogue + barrier -> the L2 port
// never idles. Extra interleaved VMEM (src prefetch, out stores) only causes
// harmless early drains: a slice always has >=8 newer ops at its vmcnt(8).
// C/D: col=lane&15, row=(lane>>4)*4+reg (m89) -> row r in lanes 0-31, r+8 in 32-63.
// Bias rides in the hi-pump accumulator init. c-state: 12 persistent VGPRs/lane.
// h-writes: xh_next BEFORE the barrier (consumed next phase); xh_self AFTER it
// (the current gemm's other waves still read xh_self's h-part pre-barrier).
template<int S, bool H2SW>
__device__ __forceinline__ void layer_step(
    u16* __restrict__ ring, const u16* __restrict__ xh_in,
    const u16* __restrict__ wsCur, const u16* __restrict__ wsNext,
    const f32x4v bia, float (&creg)[4],
    u16* __restrict__ xh_self, int din_self, u16* __restrict__ xh_next,
    float* __restrict__ h2S, int wave, int lane, int& slot)
{
  const int mrow = lane & 15, kgrp = lane >> 4;
  const int j = (wave << 4) + mrow;
  const bool hi = (kgrp < 2);
  const int aoff = mrow*RP + (kgrp << 3);
  f32x4v aI, aF, aG, aO;
  {
    float bI = hi ? bia[0] : 0.f, bF = hi ? bia[1] : 0.f;
    float bG = hi ? bia[2] : 0.f, bO = hi ? bia[3] : 0.f;
    aI = (f32x4v){bI,bI,bI,bI}; aF = (f32x4v){bF,bF,bF,bF};
    aG = (f32x4v){bG,bG,bG,bG}; aO = (f32x4v){bO,bO,bO,bO};
  }
  #pragma unroll
  for (int k=0; k<S; k++){
    asm volatile("s_waitcnt vmcnt(8)" ::: "memory");
    u16* sb = ring + slot*SLOT;
    s16x8 a  = *(const s16x8*)(xh_in + aoff + k*32);
    s16x8 b0 = *(const s16x8*)(sb + ((wave     ) << 9) + (lane << 3));
    s16x8 b1 = *(const s16x8*)(sb + ((wave +  8) << 9) + (lane << 3));
    s16x8 b2 = *(const s16x8*)(sb + ((wave + 16) << 9) + (lane << 3));
    s16x8 b3 = *(const s16x8*)(sb + ((wave + 24) << 9) + (lane << 3));
    asm volatile("s_waitcnt lgkmcnt(0)" ::: "memory");
    __builtin_amdgcn_sched_barrier(0);
    {
      const int m = k + 3;
      const u16* wsx = (m < S) ? wsCur : wsNext;
      const int ts   = (m < S) ? m : (m - S);
      dma_tile(wsx, sb, wave,      ts, lane);
      dma_tile(wsx, sb, wave +  8, ts, lane);
      dma_tile(wsx, sb, wave + 16, ts, lane);
      dma_tile(wsx, sb, wave + 24, ts, lane);
    }
    aI = __builtin_amdgcn_mfma_f32_16x16x32_bf16(a, b0, aI, 0,0,0);
    aF = __builtin_amdgcn_mfma_f32_16x16x32_bf16(a, b1, aF, 0,0,0);
    aG = __builtin_amdgcn_mfma_f32_16x16x32_bf16(a, b2, aG, 0,0,0);
    aO = __builtin_amdgcn_mfma_f32_16x16x32_bf16(a, b3, aO, 0,0,0);
    slot = (slot == 2) ? 0 : slot + 1;
  }
  // fold lo-pump rows (A rows 8-15, lanes 32-63) into hi rows
  #pragma unroll
  for (int v=0; v<4; v++){
    aI[v] += __shfl_down(aI[v], 32);
    aF[v] += __shfl_down(aF[v], 32);
    aG[v] += __shfl_down(aG[v], 32);
    aO[v] += __shfl_down(aO[v], 32);
  }
  float hvv[4];
  if (hi){
    #pragma unroll
    for (int v=0; v<4; v++){
      float iv = sigm (aI[v]);
      float fv = sigm (aF[v]);
      float gv = tanh_(aG[v]);
      float ov = sigm (aO[v]);
      creg[v] = fv*creg[v] + iv*gv;
      float hv = ov*tanh_(creg[v]);
      hvv[v] = hv;
      int r = (kgrp << 2) + v;
      if (xh_next) wr_xh(xh_next, r, j, hv);
      if (H2SW)    h2S[r*Hn + j] = hv;
    }
  }
  bar_lds();
  if (hi){
    #pragma unroll
    for (int v=0; v<4; v++) wr_xh(xh_self, (kgrp<<2)+v, din_self + j, hvv[v]);
  }
}

// OUTPUT IS FP32. 512 threads = 8 rows x 64 cols; wave w == row r so h2S reads
// are lane-broadcast (free). pred feeds straight into xh0.x for the next step.
__device__ __forceinline__ void proj_out(const float* __restrict__ h2S,
                                         const float* __restrict__ fwtS,
                                         const float* __restrict__ fbwS,
                                         u16* __restrict__ xh0,
                                         float* __restrict__ out, long b0, int t, int tid)
{
  int r = tid >> 6, d = tid & 63;
  const float* h = h2S + r*Hn;
  const float* wrow = fwtS + d*132;
  float acc = 0.f;
  #pragma unroll
  for (int kk=0; kk<Hn; kk+=4){
    f32x4v w4 = *(const f32x4v*)(wrow + kk);
    acc += h[kk]*w4[0] + h[kk+1]*w4[1] + h[kk+2]*w4[2] + h[kk+3]*w4[3];
  }
  if (d < Dn){
    float pv = acc + fbwS[d];
    out[((size_t)(b0+r)*Tn + (Tn-1-t))*Dn + d] = pv;
    wr_xh(xh0, r, d, pv);
  }
}

// 8 waves -> 2/SIMD, VGPR cap 256 (no spill risk: ~110 live). 1 WG/CU.
__global__ __launch_bounds__(NTH, 2) void lstm_kernel(
    const float* __restrict__ src, const u16* __restrict__ wsw,
    const float* __restrict__ bias, const float* __restrict__ fwt,
    const float* __restrict__ fbw, float* __restrict__ out)
{
  __shared__ __align__(16) u16   ring[3*SLOT];    // 96 KB weight ring (3 slices)
  __shared__ __align__(16) u16   xhA[3*16*RP];    // 24.75 KB per-layer A-tiles
  __shared__ __align__(16) float fwtS[FWTE];      // 33 KB fp32 (accuracy: keep f32)
  __shared__ __align__(16) float h2S[BR*Hn];      // 4 KB dec-l2 h for proj
  __shared__ __align__(16) float fbwS[64];        // 0.25 KB    (total ~158 KB)

  const int tid = threadIdx.x;
  const int wave = tid >> 6, lane = tid & 63;
  const long b0 = (long)blockIdx.x * BR;
  u16* xh0 = xhA;
  u16* xh1 = xhA + 16*RP;
  u16* xh2 = xhA + 32*RP;

  const u16* wsE0 = wsw;
  const u16* wsE1 = wsw + 1*131072;
  const u16* wsE2 = wsw + 2*131072;
  const u16* wsD0 = wsw + 3*131072;
  const u16* wsD1 = wsw + 4*131072;
  const u16* wsD2 = wsw + 5*131072;

  // persistent per-lane state: c for 3 layers (rows kgrp*4+v, col wave*16+mrow)
  float c0[4] = {0,0,0,0}, c1[4] = {0,0,0,0}, c2[4] = {0,0,0,0};
  // per-lane gate biases for this lane's column j, all 6 layers (24 VGPRs)
  const int j = (wave << 4) + (lane & 15);
  #define LDB(l) (f32x4v){ bias[(l)*G4 + j], bias[(l)*G4 + 128 + j], \
                           bias[(l)*G4 + 256 + j], bias[(l)*G4 + 384 + j] }
  f32x4v bE0 = LDB(0), bE1 = LDB(1), bE2 = LDB(2);
  f32x4v bD0 = LDB(3), bD1 = LDB(4), bD2 = LDB(5);
  #undef LDB

  // src(0) prefetch
  float sV = 0.f;
  { int r = tid >> 6, k = tid & 63;
    if (k < Dn) sV = src[((size_t)(b0+r)*Tn + 0)*Dn + k]; }

  // ---- init LDS ----
  for (int i=tid; i<FWTE; i+=NTH) fwtS[i] = fwt[i];
  if (tid < 64) fbwS[tid] = fbw[tid];
  for (int i=tid; i<3*16*RP; i+=NTH) xhA[i] = 0;   // pads stay 0 forever
  __syncthreads();
  { int r = tid >> 6, k = tid & 63;
    if (k < Dn) wr_xh(xh0, r, k, sV); }            // src(0) -> xh0.x
  __syncthreads();

  // prime ring: slices 0,1,2 of enc-l0 into slots 0,1,2 (12 batches/wave
  // in flight = steady state); running slot counter starts at 0.
  #pragma unroll
  for (int ts=0; ts<3; ts++){
    u16* db = ring + ts*SLOT;
    dma_tile(wsE0, db, wave,      ts, lane);
    dma_tile(wsE0, db, wave +  8, ts, lane);
    dma_tile(wsE0, db, wave + 16, ts, lane);
    dma_tile(wsE0, db, wave + 24, ts, lane);
  }
  int slot = 0;

  // ---------------- encoder: 3 barriers per t ----------------
  for (int t=0;t<Tn;t++){
    int tn = (t < Tn-1) ? t+1 : Tn-1;
    { int r = tid >> 6, k = tid & 63;                 // src(t+1) -> reg
      if (k < Dn) sV = src[((size_t)(b0+r)*Tn + tn)*Dn + k]; }
    layer_step<6,false>(ring, xh0, wsE0, wsE1, bE0, c0, xh0, Dn, xh1, h2S, wave, lane, slot);
    layer_step<8,false>(ring, xh1, wsE1, wsE2, bE1, c1, xh1, Hn, xh2, h2S, wave, lane, slot);
    if (t < Tn-1){                                    // xh0 has no readers during l2
      int r = tid >> 6, k = tid & 63;
      if (k < Dn) wr_xh(xh0, r, k, sV);
    }
    layer_step<8,false>(ring, xh2, wsE2, (t < Tn-1) ? wsE0 : wsD0, bE2, c2,
                        xh2, Hn, (u16*)nullptr, h2S, wave, lane, slot);
  }

  // ---------------- decoder ----------------
  // xh*.h-parts + c regs carry enc-final state. Reset xh0.x to pred(-1)=0.
  { int r = tid >> 6, k = tid & 63;
    if (k < Dn){ xh0[r*RP + k] = 0; xh0[(r+8)*RP + k] = 0; } }
  bar_lds();

  for (int t=0;t<Tn;t++){
    layer_step<6,false>(ring, xh0, wsD0, wsD1, bD0, c0, xh0, Dn, xh1, h2S, wave, lane, slot);
    layer_step<8,false>(ring, xh1, wsD1, wsD2, bD1, c1, xh1, Hn, xh2, h2S, wave, lane, slot);
    layer_step<8,true >(ring, xh2, wsD2, wsD0, bD2, c2, xh2, Hn, (u16*)nullptr,
                        h2S, wave, lane, slot);
    proj_out(h2S, fwtS, fbwS, xh0, out, b0, t, tid);
    bar_lds();
  }
}

extern "C" void kernel_launch(void* const* d_in, const int* in_sizes, int n_in,
                              void* d_out, int out_size, void* d_ws, size_t ws_size,
                              hipStream_t stream)
{
  (void)in_sizes; (void)n_in; (void)out_size; (void)ws_size;
  const float* src = (const float*)d_in[0];
  WP p;
  for (int l=0;l<3;l++){
    p.W[l]    = (const float*)d_in[1  + 3*l];
    p.U[l]    = (const float*)d_in[2  + 3*l];
    p.Bb[l]   = (const float*)d_in[3  + 3*l];
    p.W[3+l]  = (const float*)d_in[10 + 3*l];
    p.U[3+l]  = (const float*)d_in[11 + 3*l];
    p.Bb[3+l] = (const float*)d_in[12 + 3*l];
  }
  p.fW = (const float*)d_in[19];
  p.fb = (const float*)d_in[20];

  // ws: wsw u16[786432] (1.5MB) | bias f32[3072] | fwtT f32[8448] | fbw f32[64]
  u16*   wsw  = (u16*)d_ws;
  float* bias = (float*)((char*)d_ws + 6*131072*sizeof(u16));
  float* fwt  = bias + 6*512;
  float* fbw  = fwt + FWTE;

  prep_kernel<<<(PREP_TOTAL + 255)/256, 256, 0, stream>>>(p, wsw, bias, fwt, fbw);
  lstm_kernel<<<NWG, NTH, 0, stream>>>(src, wsw, bias, fwt, fbw, (float*)d_out);
}